// Round 1
// baseline (2253.465 us; speedup 1.0000x reference)
//
#include <hip/hip_runtime.h>
#include <math.h>

#define NN 50000
#define NE 800000
#define BETAF 0.1f
#define INVB 10.0f

// ---------- helpers ----------
__device__ __forceinline__ float sc_(float s, float m, float mn){
  // safe rescale for online logsumexp merging (handles m == -inf)
  return (s == 0.f) ? 0.f : s * expf(m - mn);
}

// ---------- degree histogram ----------
__launch_bounds__(256)
__global__ void k_hist(const int* __restrict__ ei, int* __restrict__ cs, int* __restrict__ cd){
  int e = blockIdx.x*256 + threadIdx.x;
  if (e >= NE) return;
  atomicAdd(&cs[ei[e]], 1);
  atomicAdd(&cd[ei[NE + e]], 1);
}

// ---------- 3-phase exclusive scan (both arrays via blockIdx.y) ----------
__launch_bounds__(256)
__global__ void k_scan_a(const int* __restrict__ inA, const int* __restrict__ inB,
                         int* __restrict__ outA, int* __restrict__ outB,
                         int* __restrict__ partA, int* __restrict__ partB, int n){
  const int* in = blockIdx.y ? inB : inA;
  int* out = blockIdx.y ? outB : outA;
  int* part = blockIdx.y ? partB : partA;
  int i = blockIdx.x*256 + threadIdx.x;
  int v = (i < n) ? in[i] : 0;
  int lane = threadIdx.x & 63, wid = threadIdx.x >> 6;
  int x = v;
  #pragma unroll
  for (int off = 1; off < 64; off <<= 1){
    int t = __shfl_up(x, off, 64);
    if (lane >= off) x += t;
  }
  __shared__ int wsum[4];
  if (lane == 63) wsum[wid] = x;
  __syncthreads();
  int base = 0;
  #pragma unroll
  for (int w = 0; w < 4; ++w) if (w < wid) base += wsum[w];
  if (i < n) out[i] = base + x - v;            // block-local exclusive
  if (threadIdx.x == 255) part[blockIdx.x] = base + x;  // block total
}

__launch_bounds__(256)
__global__ void k_scan_b(int* __restrict__ partA, int* __restrict__ partB, int np){
  int* part = blockIdx.y ? partB : partA;
  int i = threadIdx.x;
  int v = (i < np) ? part[i] : 0;
  int lane = threadIdx.x & 63, wid = threadIdx.x >> 6;
  int x = v;
  #pragma unroll
  for (int off = 1; off < 64; off <<= 1){
    int t = __shfl_up(x, off, 64);
    if (lane >= off) x += t;
  }
  __shared__ int wsum[4];
  if (lane == 63) wsum[wid] = x;
  __syncthreads();
  int base = 0;
  #pragma unroll
  for (int w = 0; w < 4; ++w) if (w < wid) base += wsum[w];
  if (i < np) part[i] = base + x - v;          // exclusive scan in place
}

__launch_bounds__(256)
__global__ void k_scan_c(int* __restrict__ outA, int* __restrict__ outB,
                         int* __restrict__ curA, int* __restrict__ curB,
                         const int* __restrict__ partA, const int* __restrict__ partB, int n){
  int* out = blockIdx.y ? outB : outA;
  int* cur = blockIdx.y ? curB : curA;
  const int* part = blockIdx.y ? partB : partA;
  int i = blockIdx.x*256 + threadIdx.x;
  if (i < n){
    int f = out[i] + part[blockIdx.x];
    out[i] = f;
    cur[i] = f;           // cursor copy for the scatter pass
  }
  if (blockIdx.x == 0 && threadIdx.x == 0) out[n] = NE;
}

// ---------- CSR scatter ----------
__launch_bounds__(256)
__global__ void k_scatter(const int* __restrict__ ei, int* __restrict__ cur_s, int* __restrict__ cur_d,
                          int* __restrict__ rank_s, int* __restrict__ dst_csr,
                          int* __restrict__ src_dord, int* __restrict__ rs_dord){
  int e = blockIdx.x*256 + threadIdx.x;
  if (e >= NE) return;
  int s = ei[e], d = ei[NE + e];
  int js = atomicAdd(&cur_s[s], 1);
  rank_s[e] = js;
  dst_csr[js] = d;
  int jd = atomicAdd(&cur_d[d], 1);
  src_dord[jd] = s;
  rs_dord[jd] = js;
}

// ---------- GEMM: C[M,128] = A[M,128] @ B[128,128], B staged in LDS (swizzled) ----------
__launch_bounds__(256)
__global__ void k_gemm128(const float* __restrict__ A, const float* __restrict__ B,
                          float* __restrict__ C, int M){
  __shared__ float4 Bs[128*32];   // 64 KB
  for (int i = threadIdx.x; i < 128*32; i += 256){
    int k = i >> 5, c4 = i & 31;
    int sw = (c4 >> 1) | ((c4 & 1) << 4);   // even c4 -> 0..15, odd -> 16..31 (2-way banks)
    Bs[(k << 5) | sw] = ((const float4*)B)[i];
  }
  __syncthreads();
  int j = threadIdx.x & 15;                   // col group (8 cols)
  int row0 = blockIdx.x*128 + ((threadIdx.x >> 4) << 3);  // 8 rows per thread
  const float* ap[8];
  #pragma unroll
  for (int r = 0; r < 8; ++r){
    int row = row0 + r; if (row > M-1) row = M-1;
    ap[r] = A + (size_t)row*128;
  }
  float acc[8][8];
  #pragma unroll
  for (int r = 0; r < 8; ++r){
    #pragma unroll
    for (int c = 0; c < 8; ++c) acc[r][c] = 0.f;
  }
  for (int k0 = 0; k0 < 128; k0 += 4){
    float4 a[8];
    #pragma unroll
    for (int r = 0; r < 8; ++r) a[r] = *(const float4*)(ap[r] + k0);
    #pragma unroll
    for (int kk = 0; kk < 4; ++kk){
      float4 b0 = Bs[((k0+kk) << 5) + j];
      float4 b1 = Bs[((k0+kk) << 5) + 16 + j];
      #pragma unroll
      for (int r = 0; r < 8; ++r){
        float av = (kk==0)?a[r].x:(kk==1)?a[r].y:(kk==2)?a[r].z:a[r].w;
        acc[r][0] += av*b0.x; acc[r][1] += av*b0.y;
        acc[r][2] += av*b0.z; acc[r][3] += av*b0.w;
        acc[r][4] += av*b1.x; acc[r][5] += av*b1.y;
        acc[r][6] += av*b1.z; acc[r][7] += av*b1.w;
      }
    }
  }
  int colg = j*8;
  #pragma unroll
  for (int r = 0; r < 8; ++r){
    int row = row0 + r;
    if (row < M){
      float4* o = (float4*)(C + (size_t)row*128 + colg);
      o[0] = make_float4(acc[r][0],acc[r][1],acc[r][2],acc[r][3]);
      o[1] = make_float4(acc[r][4],acc[r][5],acc[r][6],acc[r][7]);
    }
  }
}

// ---------- attention logit coefficients per node/head ----------
__launch_bounds__(256)
__global__ void k_al(const float* __restrict__ H, const float* __restrict__ a_s,
                     const float* __restrict__ a_d, float* __restrict__ alS, float* __restrict__ alD){
  int i = blockIdx.x*256 + threadIdx.x;   // over N*8
  if (i >= NN*8) return;
  int n = i >> 3, h = i & 7;
  const float* hp = H + (size_t)n*128 + h*16;
  float s = 0.f, d = 0.f;
  #pragma unroll
  for (int k = 0; k < 16; ++k){
    float v = hp[k];
    s += v * a_s[h*16 + k];
    d += v * a_d[h*16 + k];
  }
  alS[i] = s; alD[i] = d;
}

// ---------- fused per-dst softmax over incoming edges (no atomics) ----------
// wave per node; lane = slot*8 + head; online lse per head, then write attn & head-mean
template<bool STORE_ATTN>
__launch_bounds__(256)
__global__ void k_attsm(const int* __restrict__ row_d, const int* __restrict__ src_dord,
                        const int* __restrict__ rs_dord,
                        const float* __restrict__ alS, const float* __restrict__ alD,
                        float* __restrict__ attn_dst, float* __restrict__ a_csr){
  int node = blockIdx.x*4 + (threadIdx.x >> 6);
  if (node >= NN) return;
  int lane = threadIdx.x & 63;
  int j0 = row_d[node], j1 = row_d[node+1];
  if (j0 == j1) return;
  int head = lane & 7, slot = lane >> 3;
  float ad = alD[node*8 + head];
  float m = -INFINITY, ssum = 0.f;
  for (int j = j0 + slot; j < j1; j += 8){
    int s = src_dord[j];
    float z = alS[s*8 + head] + ad;
    z = (z >= 0.f) ? z : 0.2f*z;
    float mn = fmaxf(m, z);
    ssum = sc_(ssum, m, mn) + expf(z - mn);
    m = mn;
  }
  #pragma unroll
  for (int off = 8; off < 64; off <<= 1){   // merge slots of same head
    float mo = __shfl_xor(m, off, 64);
    float so = __shfl_xor(ssum, off, 64);
    float mn = fmaxf(m, mo);
    ssum = sc_(ssum, m, mn) + sc_(so, mo, mn);
    m = mn;
  }
  float inv_s = 1.f / ssum;
  for (int j = j0 + slot; j < j1; j += 8){
    int s = src_dord[j];
    float z = alS[s*8 + head] + ad;
    z = (z >= 0.f) ? z : 0.2f*z;
    float a = expf(z - m) * inv_s;
    if (STORE_ATTN) attn_dst[(size_t)j*8 + head] = a;
    float asum = a;                          // mean over the 8 heads (same slot group)
    asum += __shfl_xor(asum, 1, 64);
    asum += __shfl_xor(asum, 2, 64);
    asum += __shfl_xor(asum, 4, 64);
    if (head == 0) a_csr[rs_dord[j]] = asum * 0.125f;
  }
}

// ---------- attention aggregation (layer 1 only) + elu ----------
__launch_bounds__(256)
__global__ void k_agg(const int* __restrict__ row_d, const int* __restrict__ src_dord,
                      const float* __restrict__ attn_dst, const float* __restrict__ H,
                      float* __restrict__ h1){
  int node = blockIdx.x*4 + (threadIdx.x >> 6);
  if (node >= NN) return;
  int lane = threadIdx.x & 63;
  int j0 = row_d[node], j1 = row_d[node+1];
  float2 acc = make_float2(0.f, 0.f);
  int head = lane >> 3;                     // dims lane*2, lane*2+1 belong to head lane/8
  for (int j = j0; j < j1; ++j){
    int s = src_dord[j];
    float a = attn_dst[(size_t)j*8 + head];
    float2 hv = *(const float2*)(H + (size_t)s*128 + lane*2);
    acc.x += a*hv.x; acc.y += a*hv.y;
  }
  acc.x = (acc.x > 0.f) ? acc.x : expm1f(acc.x);
  acc.y = (acc.y > 0.f) ? acc.y : expm1f(acc.y);
  *(float2*)(h1 + (size_t)node*128 + lane*2) = acc;
}

// ---------- per-node structural reward halves ----------
__launch_bounds__(256)
__global__ void k_nodestr(const int* __restrict__ row_s, const int* __restrict__ row_d,
                          const float* __restrict__ Ws1, float* __restrict__ pstr, float* __restrict__ qstr){
  int i = blockIdx.x*256 + threadIdx.x;     // over N*128
  if (i >= NN*128) return;
  int n = i >> 7, c = i & 127;
  float dout = (float)(row_s[n+1] - row_s[n]);
  float din  = (float)(row_d[n+1] - row_d[n]);
  pstr[i] = dout*Ws1[c]       + log1pf(dout)*Ws1[256 + c];
  qstr[i] = din *Ws1[128 + c] + log1pf(din) *Ws1[384 + c];
}

// ---------- structural reward per edge (wave per edge) ----------
__launch_bounds__(256)
__global__ void k_rstr(const int* __restrict__ ei, const float* __restrict__ pstr,
                       const float* __restrict__ qstr, const float* __restrict__ bs1,
                       const float* __restrict__ ws2, const float* __restrict__ bs2,
                       const int* __restrict__ rank_s, float* __restrict__ rstr){
  int e = blockIdx.x*4 + (threadIdx.x >> 6);
  if (e >= NE) return;
  int lane = threadIdx.x & 63;
  int s = ei[e], d = ei[NE + e];
  float2 pp = *(const float2*)(pstr + (size_t)s*128 + lane*2);
  float2 qq = *(const float2*)(qstr + (size_t)d*128 + lane*2);
  float2 bb = *(const float2*)(bs1 + lane*2);
  float2 ww = *(const float2*)(ws2 + lane*2);
  float z0 = pp.x + qq.x + bb.x;
  float z1 = pp.y + qq.y + bb.y;
  float acc = fmaxf(z0, 0.f)*ww.x + fmaxf(z1, 0.f)*ww.y;
  #pragma unroll
  for (int off = 32; off; off >>= 1) acc += __shfl_xor(acc, off, 64);
  if (lane == 0) rstr[rank_s[e]] = acc + bs2[0];
}

// ---------- semantic reward per edge + combine (wave per edge) ----------
__launch_bounds__(256)
__global__ void k_rsem(const int* __restrict__ ei, const float* __restrict__ U,
                       const float* __restrict__ V, const float* __restrict__ bm1,
                       const float* __restrict__ wm2, const float* __restrict__ bm2,
                       const float* __restrict__ lam1, const int* __restrict__ rank_s,
                       const float* __restrict__ rstr, float* __restrict__ rout){
  int e = blockIdx.x*4 + (threadIdx.x >> 6);
  if (e >= NE) return;
  int lane = threadIdx.x & 63;
  int s = ei[e], d = ei[NE + e];
  float2 uu = *(const float2*)(U + (size_t)s*128 + lane*2);
  float2 vv = *(const float2*)(V + (size_t)d*128 + lane*2);
  float2 bb = *(const float2*)(bm1 + lane*2);
  float2 ww = *(const float2*)(wm2 + lane*2);
  float z0 = uu.x + vv.x + bb.x;
  float z1 = uu.y + vv.y + bb.y;
  float acc = fmaxf(z0, 0.f)*ww.x + fmaxf(z1, 0.f)*ww.y;
  #pragma unroll
  for (int off = 32; off; off >>= 1) acc += __shfl_xor(acc, off, 64);
  if (lane == 0){
    int js = rank_s[e];
    rout[js] = rstr[js] + lam1[0]*(acc + bm2[0]);
  }
}

// ---------- soft value iteration (both hops fused); MODE 0: V-update, MODE 1: logz ----------
template<int MODE>
__launch_bounds__(256)
__global__ void k_svi(const int* __restrict__ row_s, const int* __restrict__ dst_csr,
                      const float* __restrict__ r0, const float* __restrict__ r1,
                      const float* __restrict__ V0in, const float* __restrict__ V1in,
                      float* __restrict__ out0, float* __restrict__ out1){
  int node = blockIdx.x*4 + (threadIdx.x >> 6);
  if (node >= NN) return;
  int lane = threadIdx.x & 63;
  int j0 = row_s[node], j1 = row_s[node+1];
  if (j0 == j1){
    if (MODE == 0 && lane == 0){ out0[node] = 0.f; out1[node] = 0.f; }
    return;
  }
  float m0 = -INFINITY, s0 = 0.f, m1 = -INFINITY, s1 = 0.f;
  for (int j = j0 + lane; j < j1; j += 64){
    int d = dst_csr[j];
    float q0 = (r0[j] + V0in[d]) * INVB;
    float q1 = (r1[j] + V1in[d]) * INVB;
    float mn0 = fmaxf(m0, q0);
    s0 = sc_(s0, m0, mn0) + expf(q0 - mn0); m0 = mn0;
    float mn1 = fmaxf(m1, q1);
    s1 = sc_(s1, m1, mn1) + expf(q1 - mn1); m1 = mn1;
  }
  #pragma unroll
  for (int off = 1; off < 64; off <<= 1){
    float mo = __shfl_xor(m0, off, 64), so = __shfl_xor(s0, off, 64);
    float mn = fmaxf(m0, mo);
    s0 = sc_(s0, m0, mn) + sc_(so, mo, mn); m0 = mn;
    mo = __shfl_xor(m1, off, 64); so = __shfl_xor(s1, off, 64);
    mn = fmaxf(m1, mo);
    s1 = sc_(s1, m1, mn) + sc_(so, mo, mn); m1 = mn;
  }
  if (lane == 0){
    if (MODE == 0){
      out0[node] = BETAF*(logf(s0) + m0);
      out1[node] = BETAF*(logf(s1) + m1);
    } else {
      out0[node] = logf(s0) + m0;
      out1[node] = logf(s1) + m1;
    }
  }
}

// ---------- lse over src of log(attn_mean + 1e-12), both hops ----------
__launch_bounds__(256)
__global__ void k_lseobs(const int* __restrict__ row_s, const float* __restrict__ a0,
                         const float* __restrict__ a1, float* __restrict__ lo0, float* __restrict__ lo1){
  int node = blockIdx.x*4 + (threadIdx.x >> 6);
  if (node >= NN) return;
  int lane = threadIdx.x & 63;
  int j0 = row_s[node], j1 = row_s[node+1];
  if (j0 == j1) return;
  float m0 = -INFINITY, s0 = 0.f, m1 = -INFINITY, s1 = 0.f;
  for (int j = j0 + lane; j < j1; j += 64){
    float z0 = logf(a0[j] + 1e-12f);
    float z1 = logf(a1[j] + 1e-12f);
    float mn0 = fmaxf(m0, z0);
    s0 = sc_(s0, m0, mn0) + expf(z0 - mn0); m0 = mn0;
    float mn1 = fmaxf(m1, z1);
    s1 = sc_(s1, m1, mn1) + expf(z1 - mn1); m1 = mn1;
  }
  #pragma unroll
  for (int off = 1; off < 64; off <<= 1){
    float mo = __shfl_xor(m0, off, 64), so = __shfl_xor(s0, off, 64);
    float mn = fmaxf(m0, mo);
    s0 = sc_(s0, m0, mn) + sc_(so, mo, mn); m0 = mn;
    mo = __shfl_xor(m1, off, 64); so = __shfl_xor(s1, off, 64);
    mn = fmaxf(m1, mo);
    s1 = sc_(s1, m1, mn) + sc_(so, mo, mn); m1 = mn;
  }
  if (lane == 0){
    lo0[node] = logf(s0) + m0;
    lo1[node] = logf(s1) + m1;
  }
}

// ---------- final NLL + KL score ----------
__launch_bounds__(256)
__global__ void k_final(const int* __restrict__ row_s, const int* __restrict__ dst_csr,
                        const float* __restrict__ a0, const float* __restrict__ a1,
                        const float* __restrict__ r0, const float* __restrict__ r1,
                        const float* __restrict__ V0, const float* __restrict__ V1,
                        const float* __restrict__ lz0, const float* __restrict__ lz1,
                        const float* __restrict__ lo0, const float* __restrict__ lo1,
                        float* __restrict__ out){
  int node = blockIdx.x*4 + (threadIdx.x >> 6);
  if (node >= NN) return;
  int lane = threadIdx.x & 63;
  int j0 = row_s[node], j1 = row_s[node+1];
  if (j0 == j1){
    if (lane == 0) out[1 + node] = 0.f;
    return;
  }
  float L0 = lz0[node], L1 = lz1[node];
  float O0 = lo0[node], O1 = lo1[node];
  float nll = 0.f, sca = 0.f;
  for (int j = j0 + lane; j < j1; j += 64){
    int d = dst_csr[j];
    float la0 = logf(a0[j] + 1e-12f);
    float lp0 = la0 - O0;
    float p0 = expf(lp0);
    float ls0 = (r0[j] + V0[d]) * INVB - L0;
    nll -= p0 * ls0;
    sca += p0 * (lp0 - ls0);
    float la1 = logf(a1[j] + 1e-12f);
    float lp1 = la1 - O1;
    float p1 = expf(lp1);
    float ls1 = (r1[j] + V1[d]) * INVB - L1;
    nll -= p1 * ls1;
    sca += p1 * (lp1 - ls1);
  }
  #pragma unroll
  for (int off = 32; off; off >>= 1){
    nll += __shfl_xor(nll, off, 64);
    sca += __shfl_xor(sca, off, 64);
  }
  if (lane == 0){
    out[1 + node] = sca;
    atomicAdd(out, nll * (1.f/NN));
  }
}

// =======================================================================
extern "C" void kernel_launch(void* const* d_in, const int* in_sizes, int n_in,
                              void* d_out, int out_size, void* d_ws, size_t ws_size,
                              hipStream_t stream){
  const float* x    = (const float*)d_in[0];
  const int*   ei   = (const int*)d_in[1];
  const float* W0   = (const float*)d_in[2];
  const float* as0  = (const float*)d_in[3];
  const float* ad0  = (const float*)d_in[4];
  const float* W1   = (const float*)d_in[5];
  const float* as1  = (const float*)d_in[6];
  const float* ad1  = (const float*)d_in[7];
  const float* Ws1  = (const float*)d_in[8];
  const float* bs1  = (const float*)d_in[9];
  const float* ws2  = (const float*)d_in[10];
  const float* bs2  = (const float*)d_in[11];
  const float* Wm1  = (const float*)d_in[12];
  const float* bm1  = (const float*)d_in[13];
  const float* wm2  = (const float*)d_in[14];
  const float* bm2  = (const float*)d_in[15];
  const float* lam1 = (const float*)d_in[16];
  float* out = (float*)d_out;

  char* p = (char*)d_ws;
  auto alloc = [&](size_t bytes)->void*{
    void* r = (void*)p;
    p += (bytes + 255) & ~(size_t)255;
    return r;
  };
  float* hA      = (float*)alloc((size_t)NN*128*4);  // layer-1 proj, then layer-2 proj
  float* h1      = (float*)alloc((size_t)NN*128*4);  // post-elu hidden
  float* R2      = (float*)alloc((size_t)NN*128*4);  // qstr -> u
  float* R3      = (float*)alloc((size_t)NE*8*4);    // attn_dst -> pstr -> v
  int*   rank_s  = (int*)alloc((size_t)NE*4);
  int*   dst_csr = (int*)alloc((size_t)NE*4);
  int*   src_dord= (int*)alloc((size_t)NE*4);
  int*   rs_dord = (int*)alloc((size_t)NE*4);
  int*   row_s   = (int*)alloc((size_t)(NN+1)*4);
  int*   row_d   = (int*)alloc((size_t)(NN+1)*4);
  int*   cur_s   = (int*)alloc((size_t)NN*4);
  int*   cur_d   = (int*)alloc((size_t)NN*4);
  int*   partA   = (int*)alloc(256*4);
  int*   partB   = (int*)alloc(256*4);
  float* alS     = (float*)alloc((size_t)NN*8*4);
  float* alD     = (float*)alloc((size_t)NN*8*4);
  float* acsr0   = (float*)alloc((size_t)NE*4);
  float* acsr1   = (float*)alloc((size_t)NE*4);
  float* rstr    = (float*)alloc((size_t)NE*4);
  float* rcsr0   = (float*)alloc((size_t)NE*4);
  float* rcsr1   = (float*)alloc((size_t)NE*4);
  float* V0a = (float*)alloc((size_t)NN*4);
  float* V0b = (float*)alloc((size_t)NN*4);
  float* V1a = (float*)alloc((size_t)NN*4);
  float* V1b = (float*)alloc((size_t)NN*4);
  float* lz0 = (float*)alloc((size_t)NN*4);
  float* lz1 = (float*)alloc((size_t)NN*4);
  float* lo0 = (float*)alloc((size_t)NN*4);
  float* lo1 = (float*)alloc((size_t)NN*4);

  float* attn_dst = R3;
  float* pstr = R3;
  float* qstr = R2;
  float* Ubuf = R2;
  float* Vbuf = R3;

  const int G_E    = (NE + 255)/256;      // 3125
  const int G_gemm = (NN + 127)/128;      // 391
  const int G_al   = (NN*8 + 255)/256;    // 1563
  const int G_n4   = (NN + 3)/4;          // 12500
  const int G_e4   = (NE + 3)/4;          // 200000
  const int G_nstr = (NN*128 + 255)/256;  // 25000
  const int NPART  = (NN + 255)/256;      // 196

  // ---- CSR build ----
  hipMemsetAsync(cur_s, 0, (size_t)NN*4, stream);
  hipMemsetAsync(cur_d, 0, (size_t)NN*4, stream);
  k_hist<<<G_E, 256, 0, stream>>>(ei, cur_s, cur_d);
  k_scan_a<<<dim3(NPART,2), 256, 0, stream>>>(cur_s, cur_d, row_s, row_d, partA, partB, NN);
  k_scan_b<<<dim3(1,2), 256, 0, stream>>>(partA, partB, NPART);
  k_scan_c<<<dim3(NPART,2), 256, 0, stream>>>(row_s, row_d, cur_s, cur_d, partA, partB, NN);
  k_scatter<<<G_E, 256, 0, stream>>>(ei, cur_s, cur_d, rank_s, dst_csr, src_dord, rs_dord);

  // ---- GAT layer 1 ----
  k_gemm128<<<G_gemm, 256, 0, stream>>>(x, W0, hA, NN);
  k_al<<<G_al, 256, 0, stream>>>(hA, as0, ad0, alS, alD);
  k_attsm<true><<<G_n4, 256, 0, stream>>>(row_d, src_dord, rs_dord, alS, alD, attn_dst, acsr0);
  k_agg<<<G_n4, 256, 0, stream>>>(row_d, src_dord, attn_dst, hA, h1);

  // ---- GAT layer 2 (attention only; h2 unused by reference) ----
  k_gemm128<<<G_gemm, 256, 0, stream>>>(h1, W1, hA, NN);
  k_al<<<G_al, 256, 0, stream>>>(hA, as1, ad1, alS, alD);
  k_attsm<false><<<G_n4, 256, 0, stream>>>(row_d, src_dord, rs_dord, alS, alD, nullptr, acsr1);

  // ---- structural reward ----
  k_nodestr<<<G_nstr, 256, 0, stream>>>(row_s, row_d, Ws1, pstr, qstr);
  k_rstr<<<G_e4, 256, 0, stream>>>(ei, pstr, qstr, bs1, ws2, bs2, rank_s, rstr);

  // ---- semantic rewards (factorized per-node GEMMs + per-edge dot) ----
  k_gemm128<<<G_gemm, 256, 0, stream>>>(x, Wm1, Ubuf, NN);              // u0 = x @ Wm1[:128]
  k_gemm128<<<G_gemm, 256, 0, stream>>>(x, Wm1 + 128*128, Vbuf, NN);    // v0 = x @ Wm1[128:]
  k_rsem<<<G_e4, 256, 0, stream>>>(ei, Ubuf, Vbuf, bm1, wm2, bm2, lam1, rank_s, rstr, rcsr0);
  k_gemm128<<<G_gemm, 256, 0, stream>>>(h1, Wm1, Ubuf, NN);             // u1 = h1 @ Wm1[:128]
  k_gemm128<<<G_gemm, 256, 0, stream>>>(h1, Wm1 + 128*128, Vbuf, NN);   // v1 = h1 @ Wm1[128:]
  k_rsem<<<G_e4, 256, 0, stream>>>(ei, Ubuf, Vbuf, bm1, wm2, bm2, lam1, rank_s, rstr, rcsr1);

  // ---- soft value iteration (both hops fused per pass) ----
  hipMemsetAsync(V0a, 0, (size_t)NN*4, stream);
  hipMemsetAsync(V1a, 0, (size_t)NN*4, stream);
  float* v0i = V0a; float* v0o = V0b;
  float* v1i = V1a; float* v1o = V1b;
  for (int it = 0; it < 5; ++it){
    k_svi<0><<<G_n4, 256, 0, stream>>>(row_s, dst_csr, rcsr0, rcsr1, v0i, v1i, v0o, v1o);
    float* t;
    t = v0i; v0i = v0o; v0o = t;
    t = v1i; v1i = v1o; v1o = t;
  }
  k_svi<1><<<G_n4, 256, 0, stream>>>(row_s, dst_csr, rcsr0, rcsr1, v0i, v1i, lz0, lz1);

  // ---- observed-policy normalizers ----
  k_lseobs<<<G_n4, 256, 0, stream>>>(row_s, acsr0, acsr1, lo0, lo1);

  // ---- loss + score ----
  hipMemsetAsync(out, 0, 4, stream);
  k_final<<<G_n4, 256, 0, stream>>>(row_s, dst_csr, acsr0, acsr1, rcsr0, rcsr1,
                                    v0i, v1i, lz0, lz1, lo0, lo1, out);
}

// Round 2
// 867.134 us; speedup vs baseline: 2.5988x; 2.5988x over previous
//
#include <hip/hip_runtime.h>
#include <math.h>

#define NN 50000
#define NE 800000
#define BETAF 0.1f
#define INVB 10.0f

// ---------- helpers ----------
__device__ __forceinline__ float sc_(float s, float m, float mn){
  // safe rescale for online logsumexp merging (handles m == -inf)
  return (s == 0.f) ? 0.f : s * expf(m - mn);
}
__device__ __forceinline__ void red16(float& v){
  v += __shfl_xor(v, 1, 64); v += __shfl_xor(v, 2, 64);
  v += __shfl_xor(v, 4, 64); v += __shfl_xor(v, 8, 64);
}
__device__ __forceinline__ void lse16(float& m, float& s){
  #pragma unroll
  for (int off = 1; off < 16; off <<= 1){
    float mo = __shfl_xor(m, off, 64), so = __shfl_xor(s, off, 64);
    float mn = fmaxf(m, mo);
    s = sc_(s, m, mn) + sc_(so, mo, mn); m = mn;
  }
}
__device__ __forceinline__ float reludot4(float4 z, float4 w){
  return fmaxf(z.x,0.f)*w.x + fmaxf(z.y,0.f)*w.y + fmaxf(z.z,0.f)*w.z + fmaxf(z.w,0.f)*w.w;
}
__device__ __forceinline__ float4 add3_4(float4 a, float4 b, float4 c){
  return make_float4(a.x+b.x+c.x, a.y+b.y+c.y, a.z+b.z+c.z, a.w+b.w+c.w);
}
__device__ __forceinline__ float4 lin4(float du, float4 wa, float di, float4 wb,
                                       float lo, float4 wc, float li, float4 wd, float4 b){
  return make_float4(du*wa.x + di*wb.x + lo*wc.x + li*wd.x + b.x,
                     du*wa.y + di*wb.y + lo*wc.y + li*wd.y + b.y,
                     du*wa.z + di*wb.z + lo*wc.z + li*wd.z + b.z,
                     du*wa.w + di*wb.w + lo*wc.w + li*wd.w + b.w);
}

// ---------- degree histogram ----------
__launch_bounds__(256)
__global__ void k_hist(const int* __restrict__ ei, int* __restrict__ cs, int* __restrict__ cd){
  int e = blockIdx.x*256 + threadIdx.x;
  if (e >= NE) return;
  atomicAdd(&cs[ei[e]], 1);
  atomicAdd(&cd[ei[NE + e]], 1);
}

// ---------- 3-phase exclusive scan (both arrays via blockIdx.y) ----------
__launch_bounds__(256)
__global__ void k_scan_a(const int* __restrict__ inA, const int* __restrict__ inB,
                         int* __restrict__ outA, int* __restrict__ outB,
                         int* __restrict__ partA, int* __restrict__ partB, int n){
  const int* in = blockIdx.y ? inB : inA;
  int* out = blockIdx.y ? outB : outA;
  int* part = blockIdx.y ? partB : partA;
  int i = blockIdx.x*256 + threadIdx.x;
  int v = (i < n) ? in[i] : 0;
  int lane = threadIdx.x & 63, wid = threadIdx.x >> 6;
  int x = v;
  #pragma unroll
  for (int off = 1; off < 64; off <<= 1){
    int t = __shfl_up(x, off, 64);
    if (lane >= off) x += t;
  }
  __shared__ int wsum[4];
  if (lane == 63) wsum[wid] = x;
  __syncthreads();
  int base = 0;
  #pragma unroll
  for (int w = 0; w < 4; ++w) if (w < wid) base += wsum[w];
  if (i < n) out[i] = base + x - v;            // block-local exclusive
  if (threadIdx.x == 255) part[blockIdx.x] = base + x;  // block total
}

__launch_bounds__(256)
__global__ void k_scan_b(int* __restrict__ partA, int* __restrict__ partB, int np){
  int* part = blockIdx.y ? partB : partA;
  int i = threadIdx.x;
  int v = (i < np) ? part[i] : 0;
  int lane = threadIdx.x & 63, wid = threadIdx.x >> 6;
  int x = v;
  #pragma unroll
  for (int off = 1; off < 64; off <<= 1){
    int t = __shfl_up(x, off, 64);
    if (lane >= off) x += t;
  }
  __shared__ int wsum[4];
  if (lane == 63) wsum[wid] = x;
  __syncthreads();
  int base = 0;
  #pragma unroll
  for (int w = 0; w < 4; ++w) if (w < wid) base += wsum[w];
  if (i < np) part[i] = base + x - v;          // exclusive scan in place
}

__launch_bounds__(256)
__global__ void k_scan_c(int* __restrict__ outA, int* __restrict__ outB,
                         int* __restrict__ curA, int* __restrict__ curB,
                         const int* __restrict__ partA, const int* __restrict__ partB, int n){
  int* out = blockIdx.y ? outB : outA;
  int* cur = blockIdx.y ? curB : curA;
  const int* part = blockIdx.y ? partB : partA;
  int i = blockIdx.x*256 + threadIdx.x;
  if (i < n){
    int f = out[i] + part[blockIdx.x];
    out[i] = f;
    cur[i] = f;           // cursor copy for the scatter pass
  }
  if (blockIdx.x == 0 && threadIdx.x == 0) out[n] = NE;
}

// ---------- CSR scatter ----------
__launch_bounds__(256)
__global__ void k_scatter(const int* __restrict__ ei, int* __restrict__ cur_s, int* __restrict__ cur_d,
                          int* __restrict__ src_of_j, int* __restrict__ dst_csr,
                          int* __restrict__ src_dord, int* __restrict__ rs_dord){
  int e = blockIdx.x*256 + threadIdx.x;
  if (e >= NE) return;
  int s = ei[e], d = ei[NE + e];
  int js = atomicAdd(&cur_s[s], 1);
  src_of_j[js] = s;
  dst_csr[js] = d;
  int jd = atomicAdd(&cur_d[d], 1);
  src_dord[jd] = s;
  rs_dord[jd] = js;
}

// ---------- float degree arrays ----------
__launch_bounds__(256)
__global__ void k_deg(const int* __restrict__ row_s, const int* __restrict__ row_d,
                      float* __restrict__ degf_out, float* __restrict__ degf_in){
  int n = blockIdx.x*256 + threadIdx.x;
  if (n >= NN) return;
  degf_out[n] = (float)(row_s[n+1] - row_s[n]);
  degf_in[n]  = (float)(row_d[n+1] - row_d[n]);
}

// ---------- GEMM: C[M,128] = A[M,128] @ B[128,128], B staged in LDS (swizzled) ----------
__launch_bounds__(256)
__global__ void k_gemm128(const float* __restrict__ A, const float* __restrict__ B,
                          float* __restrict__ C, int M){
  __shared__ float4 Bs[128*32];   // 64 KB
  for (int i = threadIdx.x; i < 128*32; i += 256){
    int k = i >> 5, c4 = i & 31;
    int sw = (c4 >> 1) | ((c4 & 1) << 4);   // even c4 -> 0..15, odd -> 16..31 (2-way banks)
    Bs[(k << 5) | sw] = ((const float4*)B)[i];
  }
  __syncthreads();
  int j = threadIdx.x & 15;                   // col group (8 cols)
  int row0 = blockIdx.x*128 + ((threadIdx.x >> 4) << 3);  // 8 rows per thread
  const float* ap[8];
  #pragma unroll
  for (int r = 0; r < 8; ++r){
    int row = row0 + r; if (row > M-1) row = M-1;
    ap[r] = A + (size_t)row*128;
  }
  float acc[8][8];
  #pragma unroll
  for (int r = 0; r < 8; ++r){
    #pragma unroll
    for (int c = 0; c < 8; ++c) acc[r][c] = 0.f;
  }
  for (int k0 = 0; k0 < 128; k0 += 4){
    float4 a[8];
    #pragma unroll
    for (int r = 0; r < 8; ++r) a[r] = *(const float4*)(ap[r] + k0);
    #pragma unroll
    for (int kk = 0; kk < 4; ++kk){
      float4 b0 = Bs[((k0+kk) << 5) + j];
      float4 b1 = Bs[((k0+kk) << 5) + 16 + j];
      #pragma unroll
      for (int r = 0; r < 8; ++r){
        float av = (kk==0)?a[r].x:(kk==1)?a[r].y:(kk==2)?a[r].z:a[r].w;
        acc[r][0] += av*b0.x; acc[r][1] += av*b0.y;
        acc[r][2] += av*b0.z; acc[r][3] += av*b0.w;
        acc[r][4] += av*b1.x; acc[r][5] += av*b1.y;
        acc[r][6] += av*b1.z; acc[r][7] += av*b1.w;
      }
    }
  }
  int colg = j*8;
  #pragma unroll
  for (int r = 0; r < 8; ++r){
    int row = row0 + r;
    if (row < M){
      float4* o = (float4*)(C + (size_t)row*128 + colg);
      o[0] = make_float4(acc[r][0],acc[r][1],acc[r][2],acc[r][3]);
      o[1] = make_float4(acc[r][4],acc[r][5],acc[r][6],acc[r][7]);
    }
  }
}

// ---------- attention logit coefficients per node/head ----------
__launch_bounds__(256)
__global__ void k_al(const float* __restrict__ H, const float* __restrict__ a_s,
                     const float* __restrict__ a_d, float* __restrict__ alS, float* __restrict__ alD){
  int i = blockIdx.x*256 + threadIdx.x;   // over N*8
  if (i >= NN*8) return;
  int n = i >> 3, h = i & 7;
  const float* hp = H + (size_t)n*128 + h*16;
  float s = 0.f, d = 0.f;
  #pragma unroll
  for (int k = 0; k < 16; ++k){
    float v = hp[k];
    s += v * a_s[h*16 + k];
    d += v * a_d[h*16 + k];
  }
  alS[i] = s; alD[i] = d;
}

// ---------- fused per-dst softmax over incoming edges (no atomics) ----------
// wave per node; lane = slot*8 + head; online lse per head, then write attn & head-mean
template<bool STORE_ATTN>
__launch_bounds__(256)
__global__ void k_attsm(const int* __restrict__ row_d, const int* __restrict__ src_dord,
                        const int* __restrict__ rs_dord,
                        const float* __restrict__ alS, const float* __restrict__ alD,
                        float* __restrict__ attn_dst, float* __restrict__ a_csr){
  int node = blockIdx.x*4 + (threadIdx.x >> 6);
  if (node >= NN) return;
  int lane = threadIdx.x & 63;
  int j0 = row_d[node], j1 = row_d[node+1];
  if (j0 == j1) return;
  int head = lane & 7, slot = lane >> 3;
  float ad = alD[node*8 + head];
  float m = -INFINITY, ssum = 0.f;
  for (int j = j0 + slot; j < j1; j += 8){
    int s = src_dord[j];
    float z = alS[s*8 + head] + ad;
    z = (z >= 0.f) ? z : 0.2f*z;
    float mn = fmaxf(m, z);
    ssum = sc_(ssum, m, mn) + expf(z - mn);
    m = mn;
  }
  #pragma unroll
  for (int off = 8; off < 64; off <<= 1){   // merge slots of same head
    float mo = __shfl_xor(m, off, 64);
    float so = __shfl_xor(ssum, off, 64);
    float mn = fmaxf(m, mo);
    ssum = sc_(ssum, m, mn) + sc_(so, mo, mn);
    m = mn;
  }
  float inv_s = 1.f / ssum;
  for (int j = j0 + slot; j < j1; j += 8){
    int s = src_dord[j];
    float z = alS[s*8 + head] + ad;
    z = (z >= 0.f) ? z : 0.2f*z;
    float a = expf(z - m) * inv_s;
    if (STORE_ATTN) attn_dst[(size_t)j*8 + head] = a;
    float asum = a;                          // mean over the 8 heads (same slot group)
    asum += __shfl_xor(asum, 1, 64);
    asum += __shfl_xor(asum, 2, 64);
    asum += __shfl_xor(asum, 4, 64);
    if (head == 0) a_csr[rs_dord[j]] = asum * 0.125f;
  }
}

// ---------- attention aggregation (layer 1 only) + elu; 32 lanes/node, float4 ----------
__launch_bounds__(256)
__global__ void k_agg(const int* __restrict__ row_d, const int* __restrict__ src_dord,
                      const float* __restrict__ attn_dst, const float* __restrict__ H,
                      float* __restrict__ h1){
  int node = blockIdx.x*8 + (threadIdx.x >> 5);
  if (node >= NN) return;
  int hl = threadIdx.x & 31;      // 32 lanes x float4 = 128 dims
  int head = hl >> 2;             // 4 lanes per head (16 dims)
  int j0 = row_d[node], j1 = row_d[node+1];
  const float4* Hv = (const float4*)H;
  float4 acc = make_float4(0.f,0.f,0.f,0.f);
  int j = j0;
  for (; j + 1 < j1; j += 2){
    int s0 = src_dord[j], s1 = src_dord[j+1];
    float a0 = attn_dst[(size_t)j*8 + head];
    float a1 = attn_dst[(size_t)(j+1)*8 + head];
    float4 hv0 = Hv[(size_t)s0*32 + hl];
    float4 hv1 = Hv[(size_t)s1*32 + hl];
    acc.x += a0*hv0.x + a1*hv1.x;
    acc.y += a0*hv0.y + a1*hv1.y;
    acc.z += a0*hv0.z + a1*hv1.z;
    acc.w += a0*hv0.w + a1*hv1.w;
  }
  if (j < j1){
    int s0 = src_dord[j];
    float a0 = attn_dst[(size_t)j*8 + head];
    float4 hv0 = Hv[(size_t)s0*32 + hl];
    acc.x += a0*hv0.x; acc.y += a0*hv0.y; acc.z += a0*hv0.z; acc.w += a0*hv0.w;
  }
  acc.x = (acc.x > 0.f) ? acc.x : expm1f(acc.x);
  acc.y = (acc.y > 0.f) ? acc.y : expm1f(acc.y);
  acc.z = (acc.z > 0.f) ? acc.z : expm1f(acc.z);
  acc.w = (acc.w > 0.f) ? acc.w : expm1f(acc.w);
  ((float4*)(h1 + (size_t)node*128))[hl] = acc;
}

// ---------- fused per-edge rewards (rstr inline + both rsem hops); 16 lanes/edge, CSR order ----------
__launch_bounds__(256)
__global__ void k_edge(const int* __restrict__ src_of_j, const int* __restrict__ dst_csr,
                       const float* __restrict__ degf_out, const float* __restrict__ degf_in,
                       const float* __restrict__ U0, const float* __restrict__ V0,
                       const float* __restrict__ U1, const float* __restrict__ V1,
                       const float* __restrict__ Ws1, const float* __restrict__ bs1,
                       const float* __restrict__ ws2, const float* __restrict__ bs2,
                       const float* __restrict__ bm1, const float* __restrict__ wm2,
                       const float* __restrict__ bm2, const float* __restrict__ lam1,
                       float* __restrict__ rcsr0, float* __restrict__ rcsr1){
  int j = blockIdx.x*16 + (threadIdx.x >> 4);
  if (j >= NE) return;
  int t = threadIdx.x & 15;
  int s = src_of_j[j], d = dst_csr[j];
  float du = degf_out[s], di = degf_in[d];
  float lo = log1pf(du), li = log1pf(di);
  int c2 = t*2;
  const float4* U0v=(const float4*)U0; const float4* V0v=(const float4*)V0;
  const float4* U1v=(const float4*)U1; const float4* V1v=(const float4*)V1;
  float4 u0a=U0v[(size_t)s*32+c2], u0b=U0v[(size_t)s*32+c2+1];
  float4 v0a=V0v[(size_t)d*32+c2], v0b=V0v[(size_t)d*32+c2+1];
  float4 u1a=U1v[(size_t)s*32+c2], u1b=U1v[(size_t)s*32+c2+1];
  float4 v1a=V1v[(size_t)d*32+c2], v1b=V1v[(size_t)d*32+c2+1];
  const float4* Wv=(const float4*)Ws1;
  float4 wa_a=Wv[c2],     wa_b=Wv[c2+1];       // dout coeffs
  float4 wb_a=Wv[32+c2],  wb_b=Wv[32+c2+1];    // din
  float4 wc_a=Wv[64+c2],  wc_b=Wv[64+c2+1];    // log1p(dout)
  float4 wd_a=Wv[96+c2],  wd_b=Wv[96+c2+1];    // log1p(din)
  float4 b1a=((const float4*)bs1)[c2], b1b=((const float4*)bs1)[c2+1];
  float4 w2a=((const float4*)ws2)[c2], w2b=((const float4*)ws2)[c2+1];
  float4 bma=((const float4*)bm1)[c2], bmb=((const float4*)bm1)[c2+1];
  float4 wma=((const float4*)wm2)[c2], wmb=((const float4*)wm2)[c2+1];

  float rstr = reludot4(lin4(du,wa_a, di,wb_a, lo,wc_a, li,wd_a, b1a), w2a)
             + reludot4(lin4(du,wa_b, di,wb_b, lo,wc_b, li,wd_b, b1b), w2b);
  float r0 = reludot4(add3_4(u0a,v0a,bma), wma) + reludot4(add3_4(u0b,v0b,bmb), wmb);
  float r1 = reludot4(add3_4(u1a,v1a,bma), wma) + reludot4(add3_4(u1b,v1b,bmb), wmb);
  red16(rstr); red16(r0); red16(r1);
  if (t == 0){
    float base = rstr + bs2[0];
    float lam = lam1[0], bb = bm2[0];
    rcsr0[j] = base + lam*(r0 + bb);
    rcsr1[j] = base + lam*(r1 + bb);
  }
}

// ---------- soft value iteration V-update (both hops), 16 lanes/node ----------
__launch_bounds__(256)
__global__ void k_svi(const int* __restrict__ row_s, const int* __restrict__ dst_csr,
                      const float* __restrict__ r0, const float* __restrict__ r1,
                      const float* __restrict__ V0in, const float* __restrict__ V1in,
                      float* __restrict__ out0, float* __restrict__ out1){
  int node = blockIdx.x*16 + (threadIdx.x >> 4);
  if (node >= NN) return;
  int t = threadIdx.x & 15;
  int j0 = row_s[node], j1 = row_s[node+1];
  if (j0 == j1){
    if (t == 0){ out0[node] = 0.f; out1[node] = 0.f; }
    return;
  }
  float m0 = -INFINITY, s0 = 0.f, m1 = -INFINITY, s1 = 0.f;
  for (int j = j0 + t; j < j1; j += 16){
    int d = dst_csr[j];
    float q0 = (r0[j] + V0in[d]) * INVB;
    float q1 = (r1[j] + V1in[d]) * INVB;
    float mn0 = fmaxf(m0, q0);
    s0 = sc_(s0, m0, mn0) + expf(q0 - mn0); m0 = mn0;
    float mn1 = fmaxf(m1, q1);
    s1 = sc_(s1, m1, mn1) + expf(q1 - mn1); m1 = mn1;
  }
  lse16(m0, s0); lse16(m1, s1);
  if (t == 0){
    out0[node] = BETAF*(logf(s0) + m0);
    out1[node] = BETAF*(logf(s1) + m1);
  }
}

// ---------- fused: logz (svi final) + obs-lse + NLL + KL score; 16 lanes/node ----------
__launch_bounds__(256)
__global__ void k_final2(const int* __restrict__ row_s, const int* __restrict__ dst_csr,
                         const float* __restrict__ a0, const float* __restrict__ a1,
                         const float* __restrict__ r0, const float* __restrict__ r1,
                         const float* __restrict__ V0, const float* __restrict__ V1,
                         float* __restrict__ out, float* __restrict__ partial){
  int node = blockIdx.x*16 + (threadIdx.x >> 4);
  int t = threadIdx.x & 15;
  float nll = 0.f;
  if (node < NN){
    int j0 = row_s[node], j1 = row_s[node+1];
    if (j0 == j1){
      if (t == 0) out[1 + node] = 0.f;
    } else {
      float mq0=-INFINITY, sq0=0.f, mq1=-INFINITY, sq1=0.f;
      float ma0=-INFINITY, sa0=0.f, ma1=-INFINITY, sa1=0.f;
      for (int j = j0 + t; j < j1; j += 16){
        int d = dst_csr[j];
        float q0 = (r0[j] + V0[d]) * INVB;
        float q1 = (r1[j] + V1[d]) * INVB;
        float la0 = logf(a0[j] + 1e-12f);
        float la1 = logf(a1[j] + 1e-12f);
        float mn;
        mn = fmaxf(mq0, q0); sq0 = sc_(sq0, mq0, mn) + expf(q0 - mn); mq0 = mn;
        mn = fmaxf(mq1, q1); sq1 = sc_(sq1, mq1, mn) + expf(q1 - mn); mq1 = mn;
        mn = fmaxf(ma0, la0); sa0 = sc_(sa0, ma0, mn) + expf(la0 - mn); ma0 = mn;
        mn = fmaxf(ma1, la1); sa1 = sc_(sa1, ma1, mn) + expf(la1 - mn); ma1 = mn;
      }
      lse16(mq0, sq0); lse16(mq1, sq1); lse16(ma0, sa0); lse16(ma1, sa1);
      float L0 = logf(sq0) + mq0, L1 = logf(sq1) + mq1;
      float O0 = logf(sa0) + ma0, O1 = logf(sa1) + ma1;
      float sca = 0.f;
      for (int j = j0 + t; j < j1; j += 16){
        int d = dst_csr[j];
        float la0 = logf(a0[j] + 1e-12f);
        float lp0 = la0 - O0;
        float p0 = expf(lp0);
        float ls0 = (r0[j] + V0[d]) * INVB - L0;
        nll -= p0 * ls0;
        sca += p0 * (lp0 - ls0);
        float la1 = logf(a1[j] + 1e-12f);
        float lp1 = la1 - O1;
        float p1 = expf(lp1);
        float ls1 = (r1[j] + V1[d]) * INVB - L1;
        nll -= p1 * ls1;
        sca += p1 * (lp1 - ls1);
      }
      red16(sca);
      if (t == 0) out[1 + node] = sca;
    }
  }
  // block-level nll reduction (no same-address atomics)
  #pragma unroll
  for (int off = 1; off < 64; off <<= 1) nll += __shfl_xor(nll, off, 64);
  __shared__ float wsum[4];
  if ((threadIdx.x & 63) == 0) wsum[threadIdx.x >> 6] = nll;
  __syncthreads();
  if (threadIdx.x == 0) partial[blockIdx.x] = wsum[0]+wsum[1]+wsum[2]+wsum[3];
}

// ---------- final single-block NLL sum ----------
__launch_bounds__(256)
__global__ void k_nllred(const float* __restrict__ partial, int np, float* __restrict__ out){
  float s = 0.f;
  for (int i = threadIdx.x; i < np; i += 256) s += partial[i];
  #pragma unroll
  for (int off = 1; off < 64; off <<= 1) s += __shfl_xor(s, off, 64);
  __shared__ float wsum[4];
  if ((threadIdx.x & 63) == 0) wsum[threadIdx.x >> 6] = s;
  __syncthreads();
  if (threadIdx.x == 0) out[0] = (wsum[0]+wsum[1]+wsum[2]+wsum[3]) * (1.f/NN);
}

// =======================================================================
extern "C" void kernel_launch(void* const* d_in, const int* in_sizes, int n_in,
                              void* d_out, int out_size, void* d_ws, size_t ws_size,
                              hipStream_t stream){
  const float* x    = (const float*)d_in[0];
  const int*   ei   = (const int*)d_in[1];
  const float* W0   = (const float*)d_in[2];
  const float* as0  = (const float*)d_in[3];
  const float* ad0  = (const float*)d_in[4];
  const float* W1   = (const float*)d_in[5];
  const float* as1  = (const float*)d_in[6];
  const float* ad1  = (const float*)d_in[7];
  const float* Ws1  = (const float*)d_in[8];
  const float* bs1  = (const float*)d_in[9];
  const float* ws2  = (const float*)d_in[10];
  const float* bs2  = (const float*)d_in[11];
  const float* Wm1  = (const float*)d_in[12];
  const float* bm1  = (const float*)d_in[13];
  const float* wm2  = (const float*)d_in[14];
  const float* bm2  = (const float*)d_in[15];
  const float* lam1 = (const float*)d_in[16];
  float* out = (float*)d_out;

  char* p = (char*)d_ws;
  auto alloc = [&](size_t bytes)->void*{
    void* r = (void*)p;
    p += (bytes + 255) & ~(size_t)255;
    return r;
  };
  float* hA      = (float*)alloc((size_t)NN*128*4);  // proj layer1 -> proj layer2 -> V1
  float* h1      = (float*)alloc((size_t)NN*128*4);  // post-elu hidden
  float* U0      = (float*)alloc((size_t)NN*128*4);
  float* V0buf   = (float*)alloc((size_t)NN*128*4);
  float* AT      = (float*)alloc((size_t)NE*8*4);    // attn_dst -> U1
  int*   src_of_j= (int*)alloc((size_t)NE*4);
  int*   dst_csr = (int*)alloc((size_t)NE*4);
  int*   src_dord= (int*)alloc((size_t)NE*4);
  int*   rs_dord = (int*)alloc((size_t)NE*4);
  int*   row_s   = (int*)alloc((size_t)(NN+1)*4);
  int*   row_d   = (int*)alloc((size_t)(NN+1)*4);
  int*   cur_s   = (int*)alloc((size_t)NN*4);
  int*   cur_d   = (int*)alloc((size_t)NN*4);
  int*   partA   = (int*)alloc(256*4);
  int*   partB   = (int*)alloc(256*4);
  float* degf_out= (float*)alloc((size_t)NN*4);
  float* degf_in = (float*)alloc((size_t)NN*4);
  float* alS     = (float*)alloc((size_t)NN*8*4);
  float* alD     = (float*)alloc((size_t)NN*8*4);
  float* acsr0   = (float*)alloc((size_t)NE*4);
  float* acsr1   = (float*)alloc((size_t)NE*4);
  float* rcsr0   = (float*)alloc((size_t)NE*4);
  float* rcsr1   = (float*)alloc((size_t)NE*4);
  float* V0a = (float*)alloc((size_t)NN*4);
  float* V0b = (float*)alloc((size_t)NN*4);
  float* V1a = (float*)alloc((size_t)NN*4);
  float* V1b = (float*)alloc((size_t)NN*4);
  float* nllpart = (float*)alloc((size_t)4*((NN+15)/16 + 1));

  float* attn_dst = AT;
  float* U1 = AT;        // reuse after k_agg consumes attn_dst
  float* V1 = hA;        // reuse after layer-2 k_al consumes hA

  const int G_E    = (NE + 255)/256;      // 3125
  const int G_gemm = (NN + 127)/128;      // 391
  const int G_al   = (NN*8 + 255)/256;    // 1563
  const int G_n4   = (NN + 3)/4;          // 12500 (64-lane/node kernels)
  const int G_n8   = (NN + 7)/8;          // 6250  (32-lane/node kernels)
  const int G_n16  = (NN + 15)/16;        // 3125  (16-lane/node kernels)
  const int G_e16  = (NE + 15)/16;        // 50000 (16-lane/edge kernel)
  const int NPART  = (NN + 255)/256;      // 196

  // ---- CSR build ----
  hipMemsetAsync(cur_s, 0, (size_t)NN*4, stream);
  hipMemsetAsync(cur_d, 0, (size_t)NN*4, stream);
  k_hist<<<G_E, 256, 0, stream>>>(ei, cur_s, cur_d);
  k_scan_a<<<dim3(NPART,2), 256, 0, stream>>>(cur_s, cur_d, row_s, row_d, partA, partB, NN);
  k_scan_b<<<dim3(1,2), 256, 0, stream>>>(partA, partB, NPART);
  k_scan_c<<<dim3(NPART,2), 256, 0, stream>>>(row_s, row_d, cur_s, cur_d, partA, partB, NN);
  k_scatter<<<G_E, 256, 0, stream>>>(ei, cur_s, cur_d, src_of_j, dst_csr, src_dord, rs_dord);
  k_deg<<<(NN+255)/256, 256, 0, stream>>>(row_s, row_d, degf_out, degf_in);

  // ---- GAT layer 1 ----
  k_gemm128<<<G_gemm, 256, 0, stream>>>(x, W0, hA, NN);
  k_al<<<G_al, 256, 0, stream>>>(hA, as0, ad0, alS, alD);
  k_attsm<true><<<G_n4, 256, 0, stream>>>(row_d, src_dord, rs_dord, alS, alD, attn_dst, acsr0);
  k_agg<<<G_n8, 256, 0, stream>>>(row_d, src_dord, attn_dst, hA, h1);

  // ---- GAT layer 2 (attention only; h2 unused by reference) ----
  k_gemm128<<<G_gemm, 256, 0, stream>>>(h1, W1, hA, NN);
  k_al<<<G_al, 256, 0, stream>>>(hA, as1, ad1, alS, alD);
  k_attsm<false><<<G_n4, 256, 0, stream>>>(row_d, src_dord, rs_dord, alS, alD, nullptr, acsr1);

  // ---- semantic factorized projections (hA and AT are dead now) ----
  k_gemm128<<<G_gemm, 256, 0, stream>>>(x, Wm1, U0, NN);               // u0 = x @ Wm1[:128]
  k_gemm128<<<G_gemm, 256, 0, stream>>>(x, Wm1 + 128*128, V0buf, NN);  // v0 = x @ Wm1[128:]
  k_gemm128<<<G_gemm, 256, 0, stream>>>(h1, Wm1, U1, NN);              // u1 = h1 @ Wm1[:128]
  k_gemm128<<<G_gemm, 256, 0, stream>>>(h1, Wm1 + 128*128, V1, NN);    // v1 = h1 @ Wm1[128:]

  // ---- fused per-edge rewards (rstr inline from degrees + both rsem hops) ----
  k_edge<<<G_e16, 256, 0, stream>>>(src_of_j, dst_csr, degf_out, degf_in,
                                    U0, V0buf, U1, V1,
                                    Ws1, bs1, ws2, bs2, bm1, wm2, bm2, lam1,
                                    rcsr0, rcsr1);

  // ---- soft value iteration (both hops fused per pass) ----
  hipMemsetAsync(V0a, 0, (size_t)NN*4, stream);
  hipMemsetAsync(V1a, 0, (size_t)NN*4, stream);
  float* v0i = V0a; float* v0o = V0b;
  float* v1i = V1a; float* v1o = V1b;
  for (int it = 0; it < 5; ++it){
    k_svi<<<G_n16, 256, 0, stream>>>(row_s, dst_csr, rcsr0, rcsr1, v0i, v1i, v0o, v1o);
    float* t;
    t = v0i; v0i = v0o; v0o = t;
    t = v1i; v1i = v1o; v1o = t;
  }

  // ---- fused logz + obs-lse + loss + score ----
  k_final2<<<G_n16, 256, 0, stream>>>(row_s, dst_csr, acsr0, acsr1, rcsr0, rcsr1,
                                      v0i, v1i, out, nllpart);
  k_nllred<<<1, 256, 0, stream>>>(nllpart, G_n16, out);
}

// Round 3
// 776.444 us; speedup vs baseline: 2.9023x; 1.1168x over previous
//
#include <hip/hip_runtime.h>
#include <math.h>

#define NN 50000
#define NE 800000
#define BETAF 0.1f
#define INVB 10.0f

typedef _Float16 half8v __attribute__((ext_vector_type(8)));
typedef _Float16 half4v __attribute__((ext_vector_type(4)));
typedef _Float16 half2v __attribute__((ext_vector_type(2)));
typedef float floatx4 __attribute__((ext_vector_type(4)));

// ---------- helpers ----------
__device__ __forceinline__ float sc_(float s, float m, float mn){
  return (s == 0.f) ? 0.f : s * expf(m - mn);
}
__device__ __forceinline__ void red16(float& v){
  v += __shfl_xor(v, 1, 64); v += __shfl_xor(v, 2, 64);
  v += __shfl_xor(v, 4, 64); v += __shfl_xor(v, 8, 64);
}
__device__ __forceinline__ void lse16(float& m, float& s){
  #pragma unroll
  for (int off = 1; off < 16; off <<= 1){
    float mo = __shfl_xor(m, off, 64), so = __shfl_xor(s, off, 64);
    float mn = fmaxf(m, mo);
    s = sc_(s, m, mn) + sc_(so, mo, mn); m = mn;
  }
}
__device__ __forceinline__ float dot2acc(half2v a, half2v b, float c){
#if __has_builtin(__builtin_amdgcn_fdot2)
  return __builtin_amdgcn_fdot2(a, b, c, false);
#else
  return c + (float)a[0]*(float)b[0] + (float)a[1]*(float)b[1];
#endif
}

// ---------- degree histogram ----------
__launch_bounds__(256)
__global__ void k_hist(const int* __restrict__ ei, int* __restrict__ cs, int* __restrict__ cd){
  int e = blockIdx.x*256 + threadIdx.x;
  if (e >= NE) return;
  atomicAdd(&cs[ei[e]], 1);
  atomicAdd(&cd[ei[NE + e]], 1);
}

// ---------- 3-phase exclusive scan ----------
__launch_bounds__(256)
__global__ void k_scan_a(const int* __restrict__ inA, const int* __restrict__ inB,
                         int* __restrict__ outA, int* __restrict__ outB,
                         int* __restrict__ partA, int* __restrict__ partB, int n){
  const int* in = blockIdx.y ? inB : inA;
  int* out = blockIdx.y ? outB : outA;
  int* part = blockIdx.y ? partB : partA;
  int i = blockIdx.x*256 + threadIdx.x;
  int v = (i < n) ? in[i] : 0;
  int lane = threadIdx.x & 63, wid = threadIdx.x >> 6;
  int x = v;
  #pragma unroll
  for (int off = 1; off < 64; off <<= 1){
    int t = __shfl_up(x, off, 64);
    if (lane >= off) x += t;
  }
  __shared__ int wsum[4];
  if (lane == 63) wsum[wid] = x;
  __syncthreads();
  int base = 0;
  #pragma unroll
  for (int w = 0; w < 4; ++w) if (w < wid) base += wsum[w];
  if (i < n) out[i] = base + x - v;
  if (threadIdx.x == 255) part[blockIdx.x] = base + x;
}

__launch_bounds__(256)
__global__ void k_scan_b(int* __restrict__ partA, int* __restrict__ partB, int np){
  int* part = blockIdx.y ? partB : partA;
  int i = threadIdx.x;
  int v = (i < np) ? part[i] : 0;
  int lane = threadIdx.x & 63, wid = threadIdx.x >> 6;
  int x = v;
  #pragma unroll
  for (int off = 1; off < 64; off <<= 1){
    int t = __shfl_up(x, off, 64);
    if (lane >= off) x += t;
  }
  __shared__ int wsum[4];
  if (lane == 63) wsum[wid] = x;
  __syncthreads();
  int base = 0;
  #pragma unroll
  for (int w = 0; w < 4; ++w) if (w < wid) base += wsum[w];
  if (i < np) part[i] = base + x - v;
}

__launch_bounds__(256)
__global__ void k_scan_c(int* __restrict__ outA, int* __restrict__ outB,
                         int* __restrict__ curA, int* __restrict__ curB,
                         const int* __restrict__ partA, const int* __restrict__ partB, int n){
  int* out = blockIdx.y ? outB : outA;
  int* cur = blockIdx.y ? curB : curA;
  const int* part = blockIdx.y ? partB : partA;
  int i = blockIdx.x*256 + threadIdx.x;
  if (i < n){
    int f = out[i] + part[blockIdx.x];
    out[i] = f;
    cur[i] = f;
  }
  if (blockIdx.x == 0 && threadIdx.x == 0) out[n] = NE;
}

// ---------- CSR scatter ----------
__launch_bounds__(256)
__global__ void k_scatter(const int* __restrict__ ei, int* __restrict__ cur_s, int* __restrict__ cur_d,
                          int* __restrict__ src_of_j, int* __restrict__ dst_csr,
                          int* __restrict__ src_dord, int* __restrict__ rs_dord){
  int e = blockIdx.x*256 + threadIdx.x;
  if (e >= NE) return;
  int s = ei[e], d = ei[NE + e];
  int js = atomicAdd(&cur_s[s], 1);
  src_of_j[js] = s;
  dst_csr[js] = d;
  int jd = atomicAdd(&cur_d[d], 1);
  src_dord[jd] = s;
  rs_dord[jd] = js;
}

// ---------- clamped uint8 degrees ----------
__launch_bounds__(256)
__global__ void k_deg(const int* __restrict__ row_s, const int* __restrict__ row_d,
                      unsigned char* __restrict__ d8o, unsigned char* __restrict__ d8i){
  int n = blockIdx.x*256 + threadIdx.x;
  if (n >= NN) return;
  int a = row_s[n+1] - row_s[n];
  int b = row_d[n+1] - row_d[n];
  d8o[n] = (unsigned char)(a > 127 ? 127 : a);
  d8i[n] = (unsigned char)(b > 127 ? 127 : b);
}

// ---------- weight transpose + f16 convert (W0, W1, Wm1u, Wm1v) ----------
__launch_bounds__(256)
__global__ void k_prepw(const float* __restrict__ W0, const float* __restrict__ W1,
                        const float* __restrict__ Wm1, _Float16* __restrict__ Wt){
  int idx = blockIdx.x*256 + threadIdx.x;      // mat(2b) | n(7b) | k(7b)
  if (idx >= 4*128*128) return;
  int mat = idx >> 14, rem = idx & 16383;
  int n = rem >> 7, k = rem & 127;
  const float* src = (mat == 0) ? W0 : (mat == 1) ? W1 : (mat == 2) ? Wm1 : (Wm1 + 128*128);
  Wt[idx] = (_Float16)src[k*128 + n];
}

// ---------- structural reward lookup table r_str(deg_out, deg_in), bs2 folded ----------
__launch_bounds__(256)
__global__ void k_strtab(const float* __restrict__ Ws1, const float* __restrict__ bs1,
                         const float* __restrict__ ws2, const float* __restrict__ bs2,
                         float* __restrict__ tab){
  int idx = blockIdx.x*256 + threadIdx.x;
  if (idx >= 128*128) return;
  float du = (float)(idx >> 7), di = (float)(idx & 127);
  float lo = log1pf(du), li = log1pf(di);
  float acc = 0.f;
  for (int c = 0; c < 128; ++c){
    float z = du*Ws1[c] + di*Ws1[128+c] + lo*Ws1[256+c] + li*Ws1[384+c] + bs1[c];
    acc += fmaxf(z, 0.f)*ws2[c];
  }
  tab[idx] = acc + bs2[0];
}

// ---------- MFMA GEMM: C[M,128](f16) = A[M,128] @ W, W given transposed f16 Bt[n][k] ----------
// block = 4 waves, each wave one 16-row tile, 8 col-tiles, 4 K-tiles of mfma 16x16x32
template<int AF16, int HASB>
__launch_bounds__(256)
__global__ void k_gemm(const void* __restrict__ Ap, const _Float16* __restrict__ Bt,
                       const float* __restrict__ bias, _Float16* __restrict__ C, int M){
  int wv = threadIdx.x >> 6, lane = threadIdx.x & 63;
  int m = lane & 15, q = lane >> 4;
  int row = blockIdx.x*64 + wv*16 + m;
  int arow = (row < M) ? row : (M-1);
  half8v af[4];
  if (AF16){
    const half8v* Ar = (const half8v*)((const _Float16*)Ap + (size_t)arow*128);
    #pragma unroll
    for (int kt = 0; kt < 4; ++kt) af[kt] = Ar[kt*4 + q];
  } else {
    const float* Ar = (const float*)Ap + (size_t)arow*128;
    #pragma unroll
    for (int kt = 0; kt < 4; ++kt){
      const float4* f = (const float4*)(Ar + kt*32 + q*8);
      float4 a0 = f[0], a1 = f[1];
      half8v h;
      h[0]=(_Float16)a0.x; h[1]=(_Float16)a0.y; h[2]=(_Float16)a0.z; h[3]=(_Float16)a0.w;
      h[4]=(_Float16)a1.x; h[5]=(_Float16)a1.y; h[6]=(_Float16)a1.z; h[7]=(_Float16)a1.w;
      af[kt] = h;
    }
  }
  floatx4 acc[8];
  #pragma unroll
  for (int ct = 0; ct < 8; ++ct){ acc[ct][0]=0.f; acc[ct][1]=0.f; acc[ct][2]=0.f; acc[ct][3]=0.f; }
  #pragma unroll
  for (int ct = 0; ct < 8; ++ct){
    const half8v* Br = (const half8v*)(Bt + (size_t)(ct*16 + m)*128);
    #pragma unroll
    for (int kt = 0; kt < 4; ++kt){
      acc[ct] = __builtin_amdgcn_mfma_f32_16x16x32_f16(af[kt], Br[kt*4 + q], acc[ct], 0, 0, 0);
    }
  }
  int rb = blockIdx.x*64 + wv*16 + q*4;
  #pragma unroll
  for (int ct = 0; ct < 8; ++ct){
    int col = ct*16 + m;
    float bv = HASB ? bias[col] : 0.f;
    #pragma unroll
    for (int r = 0; r < 4; ++r){
      int rr = rb + r;
      if (rr < M) C[(size_t)rr*128 + col] = (_Float16)(acc[ct][r] + bv);
    }
  }
}

// ---------- attention logit coefficients per node/head (f16 H) ----------
__launch_bounds__(256)
__global__ void k_al(const _Float16* __restrict__ H, const float* __restrict__ a_s,
                     const float* __restrict__ a_d, float* __restrict__ alS, float* __restrict__ alD){
  int i = blockIdx.x*256 + threadIdx.x;   // over N*8
  if (i >= NN*8) return;
  int n = i >> 3, h = i & 7;
  const half8v* hp = (const half8v*)(H + (size_t)n*128 + h*16);
  half8v x0 = hp[0], x1 = hp[1];
  float s = 0.f, d = 0.f;
  #pragma unroll
  for (int k = 0; k < 8; ++k){
    float v = (float)x0[k];
    s += v * a_s[h*16 + k];
    d += v * a_d[h*16 + k];
  }
  #pragma unroll
  for (int k = 0; k < 8; ++k){
    float v = (float)x1[k];
    s += v * a_s[h*16 + 8 + k];
    d += v * a_d[h*16 + 8 + k];
  }
  alS[i] = s; alD[i] = d;
}

// ---------- fused per-dst softmax over incoming edges ----------
template<bool STORE_ATTN>
__launch_bounds__(256)
__global__ void k_attsm(const int* __restrict__ row_d, const int* __restrict__ src_dord,
                        const int* __restrict__ rs_dord,
                        const float* __restrict__ alS, const float* __restrict__ alD,
                        float* __restrict__ attn_dst, float* __restrict__ a_csr){
  int node = blockIdx.x*4 + (threadIdx.x >> 6);
  if (node >= NN) return;
  int lane = threadIdx.x & 63;
  int j0 = row_d[node], j1 = row_d[node+1];
  if (j0 == j1) return;
  int head = lane & 7, slot = lane >> 3;
  float ad = alD[node*8 + head];
  float m = -INFINITY, ssum = 0.f;
  for (int j = j0 + slot; j < j1; j += 8){
    int s = src_dord[j];
    float z = alS[s*8 + head] + ad;
    z = (z >= 0.f) ? z : 0.2f*z;
    float mn = fmaxf(m, z);
    ssum = sc_(ssum, m, mn) + expf(z - mn);
    m = mn;
  }
  #pragma unroll
  for (int off = 8; off < 64; off <<= 1){
    float mo = __shfl_xor(m, off, 64);
    float so = __shfl_xor(ssum, off, 64);
    float mn = fmaxf(m, mo);
    ssum = sc_(ssum, m, mn) + sc_(so, mo, mn);
    m = mn;
  }
  float inv_s = 1.f / ssum;
  for (int j = j0 + slot; j < j1; j += 8){
    int s = src_dord[j];
    float z = alS[s*8 + head] + ad;
    z = (z >= 0.f) ? z : 0.2f*z;
    float a = expf(z - m) * inv_s;
    if (STORE_ATTN) attn_dst[(size_t)j*8 + head] = a;
    float asum = a;
    asum += __shfl_xor(asum, 1, 64);
    asum += __shfl_xor(asum, 2, 64);
    asum += __shfl_xor(asum, 4, 64);
    if (head == 0) a_csr[rs_dord[j]] = asum * 0.125f;
  }
}

// ---------- attention aggregation + elu; 32 lanes/node, f16 H, f16 h1 out ----------
__launch_bounds__(256)
__global__ void k_agg(const int* __restrict__ row_d, const int* __restrict__ src_dord,
                      const float* __restrict__ attn_dst, const _Float16* __restrict__ H,
                      _Float16* __restrict__ h1){
  int node = blockIdx.x*8 + (threadIdx.x >> 5);
  if (node >= NN) return;
  int hl = threadIdx.x & 31;      // 32 lanes x 4 dims = 128
  int head = hl >> 2;             // 8 dims... 4 lanes per 16-dim head
  int j0 = row_d[node], j1 = row_d[node+1];
  const half4v* Hv = (const half4v*)H;
  float4 acc = make_float4(0.f,0.f,0.f,0.f);
  int j = j0;
  for (; j + 1 < j1; j += 2){
    int s0 = src_dord[j], s1 = src_dord[j+1];
    float a0 = attn_dst[(size_t)j*8 + head];
    float a1 = attn_dst[(size_t)(j+1)*8 + head];
    half4v h0 = Hv[(size_t)s0*32 + hl];
    half4v h1v = Hv[(size_t)s1*32 + hl];
    acc.x += a0*(float)h0[0] + a1*(float)h1v[0];
    acc.y += a0*(float)h0[1] + a1*(float)h1v[1];
    acc.z += a0*(float)h0[2] + a1*(float)h1v[2];
    acc.w += a0*(float)h0[3] + a1*(float)h1v[3];
  }
  if (j < j1){
    int s0 = src_dord[j];
    float a0 = attn_dst[(size_t)j*8 + head];
    half4v h0 = Hv[(size_t)s0*32 + hl];
    acc.x += a0*(float)h0[0]; acc.y += a0*(float)h0[1];
    acc.z += a0*(float)h0[2]; acc.w += a0*(float)h0[3];
  }
  acc.x = (acc.x > 0.f) ? acc.x : expm1f(acc.x);
  acc.y = (acc.y > 0.f) ? acc.y : expm1f(acc.y);
  acc.z = (acc.z > 0.f) ? acc.z : expm1f(acc.z);
  acc.w = (acc.w > 0.f) ? acc.w : expm1f(acc.w);
  half4v o;
  o[0] = (_Float16)acc.x; o[1] = (_Float16)acc.y;
  o[2] = (_Float16)acc.z; o[3] = (_Float16)acc.w;
  ((half4v*)(h1 + (size_t)node*128))[hl] = o;
}

// ---------- per-edge rewards: table r_str + both semantic hops; 1 lane/edge, f16 dot2 ----------
__launch_bounds__(256)
__global__ void k_edge3(const int* __restrict__ src_of_j, const int* __restrict__ dst_csr,
                        const unsigned char* __restrict__ d8o, const unsigned char* __restrict__ d8i,
                        const float* __restrict__ tab,
                        const _Float16* __restrict__ U0, const _Float16* __restrict__ V0,
                        const _Float16* __restrict__ U1, const _Float16* __restrict__ V1,
                        const float* __restrict__ wm2, const float* __restrict__ bm2,
                        const float* __restrict__ lam1,
                        float* __restrict__ rcsr0, float* __restrict__ rcsr1){
  __shared__ _Float16 wml[128];
  if (threadIdx.x < 128) wml[threadIdx.x] = (_Float16)wm2[threadIdx.x];
  __syncthreads();
  int j = blockIdx.x*256 + threadIdx.x;
  if (j >= NE) return;
  int s = src_of_j[j], d = dst_csr[j];
  float rstr = tab[((int)d8o[s] << 7) | (int)d8i[d]];
  const half8v* u0 = (const half8v*)(U0 + (size_t)s*128);
  const half8v* v0 = (const half8v*)(V0 + (size_t)d*128);
  const half8v* u1 = (const half8v*)(U1 + (size_t)s*128);
  const half8v* v1 = (const half8v*)(V1 + (size_t)d*128);
  const half8v* wl = (const half8v*)wml;
  float r0 = 0.f, r1 = 0.f;
  #pragma unroll 4
  for (int k = 0; k < 16; ++k){
    half8v a = u0[k] + v0[k];     // bm1 folded into U at GEMM
    half8v b = u1[k] + v1[k];
    half8v w = wl[k];
    #pragma unroll
    for (int i = 0; i < 8; ++i){
      a[i] = (a[i] > (_Float16)0) ? a[i] : (_Float16)0;
      b[i] = (b[i] > (_Float16)0) ? b[i] : (_Float16)0;
    }
    #pragma unroll
    for (int c = 0; c < 4; ++c){
      half2v aa = {a[2*c], a[2*c+1]};
      half2v bb = {b[2*c], b[2*c+1]};
      half2v ww = {w[2*c], w[2*c+1]};
      r0 = dot2acc(aa, ww, r0);
      r1 = dot2acc(bb, ww, r1);
    }
  }
  float lam = lam1[0], bb2 = bm2[0];
  rcsr0[j] = rstr + lam*(r0 + bb2);
  rcsr1[j] = rstr + lam*(r1 + bb2);
}

// ---------- soft value iteration V-update (both hops), 16 lanes/node ----------
__launch_bounds__(256)
__global__ void k_svi(const int* __restrict__ row_s, const int* __restrict__ dst_csr,
                      const float* __restrict__ r0, const float* __restrict__ r1,
                      const float* __restrict__ V0in, const float* __restrict__ V1in,
                      float* __restrict__ out0, float* __restrict__ out1){
  int node = blockIdx.x*16 + (threadIdx.x >> 4);
  if (node >= NN) return;
  int t = threadIdx.x & 15;
  int j0 = row_s[node], j1 = row_s[node+1];
  if (j0 == j1){
    if (t == 0){ out0[node] = 0.f; out1[node] = 0.f; }
    return;
  }
  float m0 = -INFINITY, s0 = 0.f, m1 = -INFINITY, s1 = 0.f;
  for (int j = j0 + t; j < j1; j += 16){
    int d = dst_csr[j];
    float q0 = (r0[j] + V0in[d]) * INVB;
    float q1 = (r1[j] + V1in[d]) * INVB;
    float mn0 = fmaxf(m0, q0);
    s0 = sc_(s0, m0, mn0) + expf(q0 - mn0); m0 = mn0;
    float mn1 = fmaxf(m1, q1);
    s1 = sc_(s1, m1, mn1) + expf(q1 - mn1); m1 = mn1;
  }
  lse16(m0, s0); lse16(m1, s1);
  if (t == 0){
    out0[node] = BETAF*(logf(s0) + m0);
    out1[node] = BETAF*(logf(s1) + m1);
  }
}

// ---------- fused: logz + obs-lse + NLL + KL score; 16 lanes/node ----------
__launch_bounds__(256)
__global__ void k_final2(const int* __restrict__ row_s, const int* __restrict__ dst_csr,
                         const float* __restrict__ a0, const float* __restrict__ a1,
                         const float* __restrict__ r0, const float* __restrict__ r1,
                         const float* __restrict__ V0, const float* __restrict__ V1,
                         float* __restrict__ out, float* __restrict__ partial){
  int node = blockIdx.x*16 + (threadIdx.x >> 4);
  int t = threadIdx.x & 15;
  float nll = 0.f;
  if (node < NN){
    int j0 = row_s[node], j1 = row_s[node+1];
    if (j0 == j1){
      if (t == 0) out[1 + node] = 0.f;
    } else {
      float mq0=-INFINITY, sq0=0.f, mq1=-INFINITY, sq1=0.f;
      float ma0=-INFINITY, sa0=0.f, ma1=-INFINITY, sa1=0.f;
      for (int j = j0 + t; j < j1; j += 16){
        int d = dst_csr[j];
        float q0 = (r0[j] + V0[d]) * INVB;
        float q1 = (r1[j] + V1[d]) * INVB;
        float la0 = logf(a0[j] + 1e-12f);
        float la1 = logf(a1[j] + 1e-12f);
        float mn;
        mn = fmaxf(mq0, q0); sq0 = sc_(sq0, mq0, mn) + expf(q0 - mn); mq0 = mn;
        mn = fmaxf(mq1, q1); sq1 = sc_(sq1, mq1, mn) + expf(q1 - mn); mq1 = mn;
        mn = fmaxf(ma0, la0); sa0 = sc_(sa0, ma0, mn) + expf(la0 - mn); ma0 = mn;
        mn = fmaxf(ma1, la1); sa1 = sc_(sa1, ma1, mn) + expf(la1 - mn); ma1 = mn;
      }
      lse16(mq0, sq0); lse16(mq1, sq1); lse16(ma0, sa0); lse16(ma1, sa1);
      float L0 = logf(sq0) + mq0, L1 = logf(sq1) + mq1;
      float O0 = logf(sa0) + ma0, O1 = logf(sa1) + ma1;
      float sca = 0.f;
      for (int j = j0 + t; j < j1; j += 16){
        int d = dst_csr[j];
        float la0 = logf(a0[j] + 1e-12f);
        float lp0 = la0 - O0;
        float p0 = expf(lp0);
        float ls0 = (r0[j] + V0[d]) * INVB - L0;
        nll -= p0 * ls0;
        sca += p0 * (lp0 - ls0);
        float la1 = logf(a1[j] + 1e-12f);
        float lp1 = la1 - O1;
        float p1 = expf(lp1);
        float ls1 = (r1[j] + V1[d]) * INVB - L1;
        nll -= p1 * ls1;
        sca += p1 * (lp1 - ls1);
      }
      red16(sca);
      if (t == 0) out[1 + node] = sca;
    }
  }
  #pragma unroll
  for (int off = 1; off < 64; off <<= 1) nll += __shfl_xor(nll, off, 64);
  __shared__ float wsum[4];
  if ((threadIdx.x & 63) == 0) wsum[threadIdx.x >> 6] = nll;
  __syncthreads();
  if (threadIdx.x == 0) partial[blockIdx.x] = wsum[0]+wsum[1]+wsum[2]+wsum[3];
}

__launch_bounds__(256)
__global__ void k_nllred(const float* __restrict__ partial, int np, float* __restrict__ out){
  float s = 0.f;
  for (int i = threadIdx.x; i < np; i += 256) s += partial[i];
  #pragma unroll
  for (int off = 1; off < 64; off <<= 1) s += __shfl_xor(s, off, 64);
  __shared__ float wsum[4];
  if ((threadIdx.x & 63) == 0) wsum[threadIdx.x >> 6] = s;
  __syncthreads();
  if (threadIdx.x == 0) out[0] = (wsum[0]+wsum[1]+wsum[2]+wsum[3]) * (1.f/NN);
}

// =======================================================================
extern "C" void kernel_launch(void* const* d_in, const int* in_sizes, int n_in,
                              void* d_out, int out_size, void* d_ws, size_t ws_size,
                              hipStream_t stream){
  const float* x    = (const float*)d_in[0];
  const int*   ei   = (const int*)d_in[1];
  const float* W0   = (const float*)d_in[2];
  const float* as0  = (const float*)d_in[3];
  const float* ad0  = (const float*)d_in[4];
  const float* W1   = (const float*)d_in[5];
  const float* as1  = (const float*)d_in[6];
  const float* ad1  = (const float*)d_in[7];
  const float* Ws1  = (const float*)d_in[8];
  const float* bs1  = (const float*)d_in[9];
  const float* ws2  = (const float*)d_in[10];
  const float* bs2  = (const float*)d_in[11];
  const float* Wm1  = (const float*)d_in[12];
  const float* bm1  = (const float*)d_in[13];
  const float* wm2  = (const float*)d_in[14];
  const float* bm2  = (const float*)d_in[15];
  const float* lam1 = (const float*)d_in[16];
  float* out = (float*)d_out;

  char* p = (char*)d_ws;
  auto alloc = [&](size_t bytes)->void*{
    void* r = (void*)p;
    p += (bytes + 255) & ~(size_t)255;
    return r;
  };
  _Float16* Hh   = (_Float16*)alloc((size_t)NN*128*2);  // layer1 proj, then layer2 proj
  _Float16* h1f  = (_Float16*)alloc((size_t)NN*128*2);
  _Float16* U0h  = (_Float16*)alloc((size_t)NN*128*2);
  _Float16* V0h  = (_Float16*)alloc((size_t)NN*128*2);
  _Float16* U1h  = (_Float16*)alloc((size_t)NN*128*2);
  _Float16* V1h  = (_Float16*)alloc((size_t)NN*128*2);
  _Float16* Wt   = (_Float16*)alloc((size_t)4*128*128*2); // W0t,W1t,Wut,Wvt
  float* tab     = (float*)alloc((size_t)128*128*4);
  float* attn_dst= (float*)alloc((size_t)NE*8*4);
  int*   src_of_j= (int*)alloc((size_t)NE*4);
  int*   dst_csr = (int*)alloc((size_t)NE*4);
  int*   src_dord= (int*)alloc((size_t)NE*4);
  int*   rs_dord = (int*)alloc((size_t)NE*4);
  int*   row_s   = (int*)alloc((size_t)(NN+1)*4);
  int*   row_d   = (int*)alloc((size_t)(NN+1)*4);
  int*   cur_s   = (int*)alloc((size_t)NN*4);
  int*   cur_d   = (int*)alloc((size_t)NN*4);
  int*   partA   = (int*)alloc(256*4);
  int*   partB   = (int*)alloc(256*4);
  unsigned char* d8o = (unsigned char*)alloc(NN);
  unsigned char* d8i = (unsigned char*)alloc(NN);
  float* alS     = (float*)alloc((size_t)NN*8*4);
  float* alD     = (float*)alloc((size_t)NN*8*4);
  float* acsr0   = (float*)alloc((size_t)NE*4);
  float* acsr1   = (float*)alloc((size_t)NE*4);
  float* rcsr0   = (float*)alloc((size_t)NE*4);
  float* rcsr1   = (float*)alloc((size_t)NE*4);
  float* V0a = (float*)alloc((size_t)NN*4);
  float* V0b = (float*)alloc((size_t)NN*4);
  float* V1a = (float*)alloc((size_t)NN*4);
  float* V1b = (float*)alloc((size_t)NN*4);
  float* nllpart = (float*)alloc((size_t)4*((NN+15)/16 + 1));

  _Float16* W0t = Wt;
  _Float16* W1t = Wt + 128*128;
  _Float16* Wut = Wt + 2*128*128;
  _Float16* Wvt = Wt + 3*128*128;

  const int G_E    = (NE + 255)/256;      // 3125
  const int G_gemm = (NN + 63)/64;        // 782
  const int G_al   = (NN*8 + 255)/256;    // 1563
  const int G_n4   = (NN + 3)/4;          // 12500
  const int G_n8   = (NN + 7)/8;          // 6250
  const int G_n16  = (NN + 15)/16;        // 3125
  const int NPART  = (NN + 255)/256;      // 196

  // ---- CSR build ----
  hipMemsetAsync(cur_s, 0, (size_t)NN*4, stream);
  hipMemsetAsync(cur_d, 0, (size_t)NN*4, stream);
  k_hist<<<G_E, 256, 0, stream>>>(ei, cur_s, cur_d);
  k_scan_a<<<dim3(NPART,2), 256, 0, stream>>>(cur_s, cur_d, row_s, row_d, partA, partB, NN);
  k_scan_b<<<dim3(1,2), 256, 0, stream>>>(partA, partB, NPART);
  k_scan_c<<<dim3(NPART,2), 256, 0, stream>>>(row_s, row_d, cur_s, cur_d, partA, partB, NN);
  k_scatter<<<G_E, 256, 0, stream>>>(ei, cur_s, cur_d, src_of_j, dst_csr, src_dord, rs_dord);
  k_deg<<<(NN+255)/256, 256, 0, stream>>>(row_s, row_d, d8o, d8i);

  // ---- weight prep + structural table ----
  k_prepw<<<(4*128*128+255)/256, 256, 0, stream>>>(W0, W1, Wm1, Wt);
  k_strtab<<<(128*128+255)/256, 256, 0, stream>>>(Ws1, bs1, ws2, bs2, tab);

  // ---- GAT layer 1 ----
  k_gemm<0,0><<<G_gemm, 256, 0, stream>>>(x, W0t, nullptr, Hh, NN);
  k_al<<<G_al, 256, 0, stream>>>(Hh, as0, ad0, alS, alD);
  k_attsm<true><<<G_n4, 256, 0, stream>>>(row_d, src_dord, rs_dord, alS, alD, attn_dst, acsr0);
  k_agg<<<G_n8, 256, 0, stream>>>(row_d, src_dord, attn_dst, Hh, h1f);

  // ---- semantic projections hop 0 (A = x, fp32) ----
  k_gemm<0,1><<<G_gemm, 256, 0, stream>>>(x, Wut, bm1, U0h, NN);
  k_gemm<0,0><<<G_gemm, 256, 0, stream>>>(x, Wvt, nullptr, V0h, NN);

  // ---- GAT layer 2 (attention only; h2 unused) ---- Hh reused for layer-2 proj
  k_gemm<1,0><<<G_gemm, 256, 0, stream>>>(h1f, W1t, nullptr, Hh, NN);
  k_al<<<G_al, 256, 0, stream>>>(Hh, as1, ad1, alS, alD);
  k_attsm<false><<<G_n4, 256, 0, stream>>>(row_d, src_dord, rs_dord, alS, alD, nullptr, acsr1);

  // ---- semantic projections hop 1 (A = h1, f16) ----
  k_gemm<1,1><<<G_gemm, 256, 0, stream>>>(h1f, Wut, bm1, U1h, NN);
  k_gemm<1,0><<<G_gemm, 256, 0, stream>>>(h1f, Wvt, nullptr, V1h, NN);

  // ---- fused per-edge rewards ----
  k_edge3<<<G_E, 256, 0, stream>>>(src_of_j, dst_csr, d8o, d8i, tab,
                                   U0h, V0h, U1h, V1h,
                                   wm2, bm2, lam1, rcsr0, rcsr1);

  // ---- soft value iteration ----
  hipMemsetAsync(V0a, 0, (size_t)NN*4, stream);
  hipMemsetAsync(V1a, 0, (size_t)NN*4, stream);
  float* v0i = V0a; float* v0o = V0b;
  float* v1i = V1a; float* v1o = V1b;
  for (int it = 0; it < 5; ++it){
    k_svi<<<G_n16, 256, 0, stream>>>(row_s, dst_csr, rcsr0, rcsr1, v0i, v1i, v0o, v1o);
    float* t;
    t = v0i; v0i = v0o; v0o = t;
    t = v1i; v1i = v1o; v1o = t;
  }

  // ---- fused logz + obs-lse + loss + score ----
  k_final2<<<G_n16, 256, 0, stream>>>(row_s, dst_csr, acsr0, acsr1, rcsr0, rcsr1,
                                      v0i, v1i, out, nllpart);
  k_nllred<<<1, 256, 0, stream>>>(nllpart, G_n16, out);
}